// Round 2
// 217.519 us; speedup vs baseline: 1.1191x; 1.1191x over previous
//
#include <hip/hip_runtime.h>
#include <stdint.h>

#define NB 256
#define NL 128
#define ND1 512
#define ND2 512

#define BI 128              // i-tile width per block (n-dim of GEMM)
#define BK 64               // k-tile depth (j-dim)
#define NKT (ND2 / BK)      // 8 k-tiles
#define LDST 72             // LDS row stride (bf16 elems): 144 B rows, 16B-aligned, bank phase +4/row

typedef float float4_t __attribute__((ext_vector_type(4)));
typedef __bf16 bf16x8_t __attribute__((ext_vector_type(8)));
typedef unsigned short ushort4_t __attribute__((ext_vector_type(4)));
typedef unsigned short ushort8_t __attribute__((ext_vector_type(8)));

// fp32 -> bf16 round-to-nearest-even
__device__ __forceinline__ unsigned short f2bf(float f) {
    unsigned int u = __float_as_uint(f);
    u += 0x7FFFu + ((u >> 16) & 1u);
    return (unsigned short)(u >> 16);
}

__device__ __forceinline__ ushort4_t cvt4(float4_t v) {
    ushort4_t u;
    u.x = f2bf(v.x); u.y = f2bf(v.y); u.z = f2bf(v.z); u.w = f2bf(v.w);
    return u;
}

// Z = T2 (128 x 512, k=j) x W^T (512 x 512; B[n=i][k=j], rows k-contiguous!)
// out[b,l] = sum_i Z[l,i] * t1[b,l,i]
//
// Pipelined k-loop: register-prefetch tile k+1 during compute of tile k.
// Raw s_barrier (NOT __syncthreads) so in-flight global loads are not
// drained at the barrier; compiler inserts counted vmcnt waits on the
// register deps. lb(256,3) gives ~170 unified regs: 64 acc + 64 prefetch fit.
// All barriers are in wave-uniform control flow (kt guard is block-uniform),
// and every s_barrier is preceded by lgkmcnt(0) publishing this wave's
// LDS writes — no deadlock path, no visibility race.
__global__ __launch_bounds__(256, 3) void pdot_kernel(
    const float* __restrict__ t1, const float* __restrict__ t2,
    const int* __restrict__ pidx, const float* __restrict__ wgt,
    float* __restrict__ out)
{
    __shared__ unsigned short sA[NL * LDST];   // T2 tile bf16: [128 l][64 j + pad]
    __shared__ unsigned short sB[BI * LDST];   // W  tile bf16: [128 i][64 j + pad]

    const int g  = blockIdx.x;
    const int b  = g & (NB - 1);   // batch in low bits: all 4 i-tiles of b share g%8 (XCD) -> t1/t2 L2 reuse
    const int it = g >> 8;
    const int i0 = it * BI;

    const int t  = threadIdx.x;
    const int wv = t >> 6;         // wave 0..3 -> l-rows wv*32..wv*32+31
    const int ln = t & 63;
    const int nh = ln & 15;
    const int qd = ln >> 4;

    const int e = pidx[b];
    const float* aPtr  = t2  + (size_t)b * (NL * ND2);            // A source (l-major, j contig)
    const float* bPtr  = wgt + (size_t)e * (ND1 * ND2) + (size_t)i0 * ND2;  // B source (i-major, j contig)
    const float* t1p   = t1  + (size_t)b * (NL * ND1) + i0;       // epilogue dot operand

    float4_t acc[2][8];
    #pragma unroll
    for (int i = 0; i < 2; ++i)
        #pragma unroll
        for (int j = 0; j < 8; ++j) {
            float4_t z = {0.f, 0.f, 0.f, 0.f};
            acc[i][j] = z;
        }

    // staging map: pass p covers rows p*16..p*16+15, lane (t&15) owns one
    // 16B chunk -> fully coalesced float4, 8 passes/tile
    const int s_row = t >> 4;
    const int s_kq  = (t & 15) * 4;
    const size_t sOff = (size_t)s_row * ND2 + s_kq;

    float4_t pa[8], pb[8];   // in-flight prefetch registers (64 VGPRs)

    // ---- prologue: load+stage tile 0, issue prefetch of tile 1 ----
    #pragma unroll
    for (int p = 0; p < 8; ++p) {
        pa[p] = *(const float4_t*)(aPtr + sOff + (size_t)p * (16 * ND2));
        pb[p] = *(const float4_t*)(bPtr + sOff + (size_t)p * (16 * ND2));
    }
    #pragma unroll
    for (int p = 0; p < 8; ++p) {
        const int row = p * 16 + s_row;
        *(ushort4_t*)(&sA[row * LDST + s_kq]) = cvt4(pa[p]);
        *(ushort4_t*)(&sB[row * LDST + s_kq]) = cvt4(pb[p]);
    }
    #pragma unroll
    for (int p = 0; p < 8; ++p) {
        pa[p] = *(const float4_t*)(aPtr + sOff + BK + (size_t)p * (16 * ND2));
        pb[p] = *(const float4_t*)(bPtr + sOff + BK + (size_t)p * (16 * ND2));
    }
    __builtin_amdgcn_sched_barrier(0);
    asm volatile("s_waitcnt lgkmcnt(0)" ::: "memory");  // LDS writes of tile 0 published
    __builtin_amdgcn_sched_barrier(0);
    __builtin_amdgcn_s_barrier();              // raw barrier: prefetch loads stay in flight
    __builtin_amdgcn_sched_barrier(0);

    for (int kt = 0; kt < NKT; ++kt) {
        // ---- compute tile kt from LDS (prefetch for kt+1 flying) ----
        #pragma unroll
        for (int ks = 0; ks < 2; ++ks) {
            const int kf = ks * 32 + qd * 8;
            const int ra = wv * 32 + nh;
            bf16x8_t af0 = __builtin_bit_cast(bf16x8_t, *(ushort8_t*)(&sA[(ra     ) * LDST + kf]));
            bf16x8_t af1 = __builtin_bit_cast(bf16x8_t, *(ushort8_t*)(&sA[(ra + 16) * LDST + kf]));
            #pragma unroll
            for (int ns = 0; ns < 8; ++ns) {
                bf16x8_t bv = __builtin_bit_cast(bf16x8_t, *(ushort8_t*)(&sB[(ns * 16 + nh) * LDST + kf]));
                acc[0][ns] = __builtin_amdgcn_mfma_f32_16x16x32_bf16(af0, bv, acc[0][ns], 0, 0, 0);
                acc[1][ns] = __builtin_amdgcn_mfma_f32_16x16x32_bf16(af1, bv, acc[1][ns], 0, 0, 0);
            }
        }

        if (kt < NKT - 1) {
            __builtin_amdgcn_sched_barrier(0);
            __builtin_amdgcn_s_barrier();      // all waves done READING tile kt
            __builtin_amdgcn_sched_barrier(0);

            // write tile kt+1 (compiler inserts counted vmcnt waits on pa/pb)
            #pragma unroll
            for (int p = 0; p < 8; ++p) {
                const int row = p * 16 + s_row;
                *(ushort4_t*)(&sA[row * LDST + s_kq]) = cvt4(pa[p]);
                *(ushort4_t*)(&sB[row * LDST + s_kq]) = cvt4(pb[p]);
            }
            // issue loads for tile kt+2 — these fly across the next barrier
            if (kt < NKT - 2) {
                const size_t k0 = (size_t)(kt + 2) * BK;
                #pragma unroll
                for (int p = 0; p < 8; ++p) {
                    pa[p] = *(const float4_t*)(aPtr + sOff + k0 + (size_t)p * (16 * ND2));
                    pb[p] = *(const float4_t*)(bPtr + sOff + k0 + (size_t)p * (16 * ND2));
                }
            }
            __builtin_amdgcn_sched_barrier(0);
            asm volatile("s_waitcnt lgkmcnt(0)" ::: "memory");  // tile kt+1 writes published
            __builtin_amdgcn_sched_barrier(0);
            __builtin_amdgcn_s_barrier();
            __builtin_amdgcn_sched_barrier(0);
        }
    }

    // epilogue: out[b,l] += sum over this i-tile of Z[l,i]*t1[l,i]
    // C/D: col(n=i) = ns*16+nh, row(m=l) = qd*4+r (+ms*16+wv*32)
    #pragma unroll
    for (int ms = 0; ms < 2; ++ms) {
        #pragma unroll
        for (int r = 0; r < 4; ++r) {
            const int row = wv * 32 + ms * 16 + qd * 4 + r;
            float ps = 0.f;
            #pragma unroll
            for (int ns = 0; ns < 8; ++ns) {
                const float tv = t1p[(size_t)row * ND1 + ns * 16 + nh];
                ps += acc[ms][ns][r] * tv;
            }
            ps += __shfl_xor(ps, 1);
            ps += __shfl_xor(ps, 2);
            ps += __shfl_xor(ps, 4);
            ps += __shfl_xor(ps, 8);
            if (nh == 0) atomicAdd(&out[b * NL + row], ps);
        }
    }
}

extern "C" void kernel_launch(void* const* d_in, const int* in_sizes, int n_in,
                              void* d_out, int out_size, void* d_ws, size_t ws_size,
                              hipStream_t stream)
{
    const float* t1  = (const float*)d_in[0];
    const float* t2  = (const float*)d_in[1];
    const int* pidx  = (const int*)d_in[2];
    const float* wgt = (const float*)d_in[3];
    float* out = (float*)d_out;

    hipMemsetAsync(out, 0, (size_t)out_size * sizeof(float), stream);
    pdot_kernel<<<dim3(NB * (ND1 / BI)), dim3(256), 0, stream>>>(t1, t2, pidx, wgt, out);
}